// Round 1
// baseline (560.326 us; speedup 1.0000x reference)
//
#include <hip/hip_runtime.h>
#include <hip/hip_bf16.h>
#include <math.h>

// Problem constants
#define B_    2
#define D_    256
#define NH_   8
#define NL_   4
#define NP_   4
#define HD_   32
#define S_    13294
#define L_    13294
#define M_    (B_ * L_)   // 26588 rows for all row-major GEMMs

// Level shapes (H, W) and start offsets into S
__device__ __constant__ int   c_H[NL_]     = {100, 50, 25, 13};
__device__ __constant__ int   c_W[NL_]     = {100, 50, 25, 13};
__device__ __constant__ int   c_start[NL_] = {0, 10000, 12500, 13125};

// ---------------------------------------------------------------------------
// Tiled fp32 GEMM: C[M,N] = A[M,256] * W[256,N] + bias[N]
// 64x64 tile per block, 256 threads, 4x4 microtile per thread, BK=16.
// ---------------------------------------------------------------------------
__global__ __launch_bounds__(256) void gemm_k256(
    const float* __restrict__ A, const float* __restrict__ W,
    const float* __restrict__ bias, float* __restrict__ C,
    int M, int N)
{
    __shared__ float As[16][64];   // [kk][row]  (A transposed in LDS)
    __shared__ float Ws[16][64];   // [kk][col]

    const int tid = threadIdx.x;
    const int rowBase = blockIdx.x * 64;
    const int colBase = blockIdx.y * 64;
    const int tx = tid & 15;       // 0..15 -> 4 cols each
    const int ty = tid >> 4;       // 0..15 -> 4 rows each

    // A-tile load mapping: one float4 per thread
    const int ar = tid >> 2;            // 0..63 (row within tile)
    const int ak = (tid & 3) * 4;       // 0,4,8,12 (k within tile)
    // W-tile load mapping: one float4 per thread
    const int wk = tid >> 4;            // 0..15
    const int wc = (tid & 15) * 4;      // 0..60

    float acc[4][4] = {};

    for (int k0 = 0; k0 < 256; k0 += 16) {
        const int grow = rowBase + ar;
        float4 av = make_float4(0.f, 0.f, 0.f, 0.f);
        if (grow < M)
            av = *reinterpret_cast<const float4*>(A + (size_t)grow * 256 + k0 + ak);
        As[ak + 0][ar] = av.x;
        As[ak + 1][ar] = av.y;
        As[ak + 2][ar] = av.z;
        As[ak + 3][ar] = av.w;

        float4 wv = *reinterpret_cast<const float4*>(W + (size_t)(k0 + wk) * N + colBase + wc);
        *reinterpret_cast<float4*>(&Ws[wk][wc]) = wv;

        __syncthreads();

#pragma unroll
        for (int kk = 0; kk < 16; ++kk) {
            float4 a = *reinterpret_cast<const float4*>(&As[kk][ty * 4]);
            float4 b = *reinterpret_cast<const float4*>(&Ws[kk][tx * 4]);
            float ai[4] = {a.x, a.y, a.z, a.w};
            float bj[4] = {b.x, b.y, b.z, b.w};
#pragma unroll
            for (int i = 0; i < 4; ++i)
#pragma unroll
                for (int j = 0; j < 4; ++j)
                    acc[i][j] += ai[i] * bj[j];
        }
        __syncthreads();
    }

    const float4 bv = *reinterpret_cast<const float4*>(bias + colBase + tx * 4);
    const float bj[4] = {bv.x, bv.y, bv.z, bv.w};
#pragma unroll
    for (int i = 0; i < 4; ++i) {
        const int r = rowBase + ty * 4 + i;
        if (r < M) {
            float4 o;
            o.x = acc[i][0] + bj[0];
            o.y = acc[i][1] + bj[1];
            o.z = acc[i][2] + bj[2];
            o.w = acc[i][3] + bj[3];
            *reinterpret_cast<float4*>(C + (size_t)r * N + colBase + tx * 4) = o;
        }
    }
}

// ---------------------------------------------------------------------------
// Deformable sampling + softmax + weighted accumulation.
// One block per (b,q). 256 threads.
//   Phase 1 (128 threads): softmax over the 16 (lvl,p) logits per head,
//     compute pixel-space sample locations, emit 4 bilinear corners
//     (global s-index or -1, fused weight = attn * corner_w) into LDS.
//   Phase 2 (256 threads, h = tid>>5, d = tid&31): accumulate 64 weighted
//     loads from val[b, s, h, d] (val layout [B,S,NH,HD], 128B contiguous
//     per (b,s,h) so each 32-lane group is coalesced).
// ---------------------------------------------------------------------------
__global__ __launch_bounds__(256) void deform_sample(
    const float* __restrict__ val,     // [B,S,NH,HD]
    const float* __restrict__ refp,    // [B,L,NL,2]
    const float* __restrict__ off,     // [B,L,256]
    const float* __restrict__ logits,  // [B,L,128]
    float* __restrict__ acc)           // [B,L,256]
{
    const int bq  = blockIdx.x;        // b*L + q
    const int b   = bq / L_;
    const int tid = threadIdx.x;

    __shared__ float sLog[128];
    __shared__ float sW[128][4];
    __shared__ int   sIdx[128][4];

    if (tid < 128)
        sLog[tid] = logits[(size_t)bq * 128 + tid];
    __syncthreads();

    if (tid < 128) {
        const int h   = tid >> 4;
        const int lp  = tid & 15;
        const int lvl = lp >> 2;
        const int p   = lp & 3;

        // softmax over the head's 16 logits
        float m = -1e30f;
#pragma unroll
        for (int i = 0; i < 16; ++i) m = fmaxf(m, sLog[h * 16 + i]);
        float sum = 0.f;
#pragma unroll
        for (int i = 0; i < 16; ++i) sum += __expf(sLog[h * 16 + i] - m);
        const float wgt = __expf(sLog[tid] - m) / sum;

        // sample location in pixel space
        const int Wi = c_W[lvl], Hi = c_H[lvl], st = c_start[lvl];
        const float Wf = (float)Wi, Hf = (float)Hi;
        const float rx = refp[((size_t)bq * NL_ + lvl) * 2 + 0];
        const float ry = refp[((size_t)bq * NL_ + lvl) * 2 + 1];
        const float ox = off[(size_t)bq * 256 + h * 32 + lvl * 8 + p * 2 + 0];
        const float oy = off[(size_t)bq * 256 + h * 32 + lvl * 8 + p * 2 + 1];
        // loc = ref + off/[W,H]; pixel x = loc_x*W - 0.5 = rx*W + ox - 0.5
        const float x = rx * Wf + ox - 0.5f;
        const float y = ry * Hf + oy - 0.5f;

        const float x0f = floorf(x), y0f = floorf(y);
        const int   x0 = (int)x0f,   y0 = (int)y0f;
        const float wx1 = x - x0f, wx0 = 1.f - wx1;
        const float wy1 = y - y0f, wy0 = 1.f - wy1;

        const int cx[4] = {x0, x0 + 1, x0,     x0 + 1};
        const int cy[4] = {y0, y0,     y0 + 1, y0 + 1};
        const float cw[4] = {wx0 * wy0, wx1 * wy0, wx0 * wy1, wx1 * wy1};
#pragma unroll
        for (int c = 0; c < 4; ++c) {
            const bool inb = (cx[c] >= 0) & (cx[c] < Wi) & (cy[c] >= 0) & (cy[c] < Hi);
            sIdx[tid][c] = inb ? (st + cy[c] * Wi + cx[c]) : -1;
            sW[tid][c]   = wgt * cw[c];
        }
    }
    __syncthreads();

    const int h = tid >> 5;
    const int d = tid & 31;
    const float* vbase = val + (size_t)b * S_ * 256 + h * 32 + d;

    float a = 0.f;
#pragma unroll
    for (int lp = 0; lp < 16; ++lp) {
        const int e = h * 16 + lp;
#pragma unroll
        for (int c = 0; c < 4; ++c) {
            const int idx = sIdx[e][c];
            if (idx >= 0)
                a += sW[e][c] * vbase[(size_t)idx * 256];
        }
    }
    acc[(size_t)bq * 256 + tid] = a;
}

// ---------------------------------------------------------------------------
extern "C" void kernel_launch(void* const* d_in, const int* in_sizes, int n_in,
                              void* d_out, int out_size, void* d_ws, size_t ws_size,
                              hipStream_t stream) {
    const float* query  = (const float*)d_in[0];   // [B,L,256]
    const float* refp   = (const float*)d_in[1];   // [B,L,4,2]
    const float* value  = (const float*)d_in[2];   // [B,S,256]
    const float* W_val  = (const float*)d_in[3];   // [256,256]
    const float* b_val  = (const float*)d_in[4];   // [256]
    const float* W_off  = (const float*)d_in[5];   // [256,256]
    const float* b_off  = (const float*)d_in[6];   // [256]
    const float* W_attn = (const float*)d_in[7];   // [256,128]
    const float* b_attn = (const float*)d_in[8];   // [128]
    const float* W_out  = (const float*)d_in[9];   // [256,256]
    const float* b_out  = (const float*)d_in[10];  // [256]
    float* out = (float*)d_out;                    // [B,L,256]

    float* ws      = (float*)d_ws;
    float* val_ws  = ws;                            // B*S*256   = 6,806,528
    float* off_ws  = val_ws  + (size_t)B_ * S_ * 256;  // 6,806,528
    float* attn_ws = off_ws  + (size_t)B_ * L_ * 256;  // 3,403,264
    float* acc_ws  = attn_ws + (size_t)B_ * L_ * 128;  // 6,806,528

    const int M = M_;
    dim3 blk(256);
    dim3 gA((M + 63) / 64, 256 / 64);
    dim3 gC((M + 63) / 64, 128 / 64);

    // 1. value projection
    gemm_k256<<<gA, blk, 0, stream>>>(value, W_val, b_val, val_ws, M, 256);
    // 2. offset projection
    gemm_k256<<<gA, blk, 0, stream>>>(query, W_off, b_off, off_ws, M, 256);
    // 3. attention logits
    gemm_k256<<<gC, blk, 0, stream>>>(query, W_attn, b_attn, attn_ws, M, 128);
    // 4. softmax + bilinear sampling + accumulate
    deform_sample<<<dim3(M), blk, 0, stream>>>(val_ws, refp, off_ws, attn_ws, acc_ws);
    // 5. output projection
    gemm_k256<<<gA, blk, 0, stream>>>(acc_ws, W_out, b_out, out, M, 256);
}

// Round 2
// 318.060 us; speedup vs baseline: 1.7617x; 1.7617x over previous
//
#include <hip/hip_runtime.h>
#include <hip/hip_bf16.h>
#include <math.h>
#include <type_traits>

// Problem constants
#define B_    2
#define D_    256
#define NH_   8
#define NL_   4
#define NP_   4
#define HD_   32
#define S_    13294
#define L_    13294
#define M_    (B_ * L_)   // 26588 rows for all row-major GEMMs

__device__ __constant__ int c_H[NL_]     = {100, 50, 25, 13};
__device__ __constant__ int c_W[NL_]     = {100, 50, 25, 13};
__device__ __constant__ int c_start[NL_] = {0, 10000, 12500, 13125};

typedef __attribute__((ext_vector_type(8))) short  short8;   // 8 bf16
typedef __attribute__((ext_vector_type(4))) float  float4v;  // MFMA acc

// ---------------------------------------------------------------------------
// fp32 -> bf16 bulk convert (n divisible by 4)
// ---------------------------------------------------------------------------
__global__ __launch_bounds__(256) void f32_to_bf16(
    const float* __restrict__ in, __hip_bfloat16* __restrict__ out, int n4)
{
    for (int i = blockIdx.x * blockDim.x + threadIdx.x; i < n4;
         i += gridDim.x * blockDim.x) {
        float4 v = *reinterpret_cast<const float4*>(in + (size_t)i * 4);
        __hip_bfloat16* o = out + (size_t)i * 4;
        o[0] = __float2bfloat16(v.x);
        o[1] = __float2bfloat16(v.y);
        o[2] = __float2bfloat16(v.z);
        o[3] = __float2bfloat16(v.w);
    }
}

// ---------------------------------------------------------------------------
// W[K,N] fp32 -> WT[N,K] bf16 (tiny: weights only)
// ---------------------------------------------------------------------------
__global__ __launch_bounds__(256) void transpose_w_bf16(
    const float* __restrict__ W, __hip_bfloat16* __restrict__ WT, int K, int N)
{
    int i = blockIdx.x * blockDim.x + threadIdx.x;
    if (i < N * K) {
        int n = i / K, k = i - n * K;
        WT[i] = __float2bfloat16(W[(size_t)k * N + n]);
    }
}

// ---------------------------------------------------------------------------
// bf16 MFMA GEMM: C[M,N] = A[M,256] * WT[N,256]^T + bias[N]
// 128x128 tile, 256 threads (4 waves in 2x2), 16x16x32 bf16 MFMA.
// Fragment maps (HW-verified, learn_hip m89/m91):
//   A-operand: m = lane&15, k = (lane>>4)*8 + j   (8 contiguous bf16 -> b128)
//   B-operand: n = lane&15, k = (lane>>4)*8 + j   (from WT rows)
//   C/D:       n = lane&15, m = (lane>>4)*4 + reg
// LDS rows padded to 40 bf16 (80 B): 16B-aligned b128 reads, conflict-free.
// ---------------------------------------------------------------------------
template <typename OutT>
__global__ __launch_bounds__(256) void gemm_mfma(
    const __hip_bfloat16* __restrict__ A,
    const __hip_bfloat16* __restrict__ WT,
    const float* __restrict__ bias,
    OutT* __restrict__ C,
    int M, int N)
{
    __shared__ __hip_bfloat16 As[128][40];
    __shared__ __hip_bfloat16 Bs[128][40];

    const int tid  = threadIdx.x;
    const int lane = tid & 63;
    const int wave = tid >> 6;
    const int rowBase = blockIdx.x * 128;
    const int colBase = blockIdx.y * 128;
    const int wm = (wave >> 1) * 64;
    const int wn = (wave & 1) * 64;

    float4v acc[4][4] = {};

    const int fr = lane & 15;
    const int fk = (lane >> 4) * 8;

    for (int k0 = 0; k0 < 256; k0 += 32) {
        __syncthreads();
        // stage: 512 16B-chunks per matrix, 2 per thread
#pragma unroll
        for (int i = 0; i < 2; ++i) {
            const int c  = tid + i * 256;
            const int r  = c >> 2;          // 0..127
            const int ko = (c & 3) * 8;     // 0,8,16,24
            const int gr = rowBase + r;
            short8 va = {};
            if (gr < M)
                va = *reinterpret_cast<const short8*>(A + (size_t)gr * 256 + k0 + ko);
            *reinterpret_cast<short8*>(&As[r][ko]) = va;
            const int gc = colBase + r;     // N is a multiple of 128
            short8 vb = *reinterpret_cast<const short8*>(WT + (size_t)gc * 256 + k0 + ko);
            *reinterpret_cast<short8*>(&Bs[r][ko]) = vb;
        }
        __syncthreads();

        short8 af[4], bf[4];
#pragma unroll
        for (int t = 0; t < 4; ++t) {
            af[t] = *reinterpret_cast<const short8*>(&As[wm + t * 16 + fr][fk]);
            bf[t] = *reinterpret_cast<const short8*>(&Bs[wn + t * 16 + fr][fk]);
        }
#pragma unroll
        for (int mt = 0; mt < 4; ++mt)
#pragma unroll
            for (int nt = 0; nt < 4; ++nt)
                acc[mt][nt] = __builtin_amdgcn_mfma_f32_16x16x32_bf16(
                    af[mt], bf[nt], acc[mt][nt], 0, 0, 0);
    }

    const int dn  = lane & 15;
    const int dm0 = (lane >> 4) * 4;
#pragma unroll
    for (int mt = 0; mt < 4; ++mt) {
#pragma unroll
        for (int nt = 0; nt < 4; ++nt) {
            const int col = colBase + wn + nt * 16 + dn;
            const float bv = bias[col];
#pragma unroll
            for (int r = 0; r < 4; ++r) {
                const int row = rowBase + wm + mt * 16 + dm0 + r;
                if (row < M) {
                    const float v = acc[mt][nt][r] + bv;
                    if constexpr (std::is_same<OutT, float>::value)
                        C[(size_t)row * N + col] = v;
                    else
                        C[(size_t)row * N + col] = __float2bfloat16(v);
                }
            }
        }
    }
}

// ---------------------------------------------------------------------------
// Deformable sampling: softmax + bilinear gather (bf16 val) + accumulate.
// 2 queries per block, 256 threads.
//   Phase 1: thread = (ql, h, lvl, p): softmax weight + 4 corner (idx, w) -> LDS
//   Phase 2: thread = (ql, h, dpair): 64 gathers of bf16x2, fp32 accumulate,
//            bf16 store to acc[B,L,256].
// ---------------------------------------------------------------------------
__global__ __launch_bounds__(256) void deform_sample_bf16(
    const __hip_bfloat16* __restrict__ val,  // [B,S,256] bf16
    const float* __restrict__ refp,          // [B,L,4,2]
    const float* __restrict__ off,           // [B,L,256]
    const float* __restrict__ logits,        // [B,L,128]
    __hip_bfloat16* __restrict__ acc)        // [B,L,256] bf16
{
    const int tid  = threadIdx.x;
    const int ql   = tid >> 7;              // 0/1
    const int t128 = tid & 127;
    const int bq   = blockIdx.x * 2 + ql;
    const int b    = bq / L_;

    __shared__ float sLog[2][128];
    __shared__ float sW[2][128][4];
    __shared__ int   sIdx[2][128][4];

    sLog[ql][t128] = logits[(size_t)bq * 128 + t128];
    __syncthreads();

    {
        const int h   = t128 >> 4;
        const int lp  = t128 & 15;
        const int lvl = lp >> 2;
        const int p   = lp & 3;

        float m = -1e30f;
#pragma unroll
        for (int i = 0; i < 16; ++i) m = fmaxf(m, sLog[ql][h * 16 + i]);
        float sum = 0.f;
#pragma unroll
        for (int i = 0; i < 16; ++i) sum += __expf(sLog[ql][h * 16 + i] - m);
        const float wgt = __expf(sLog[ql][t128] - m) / sum;

        const int Wi = c_W[lvl], Hi = c_H[lvl], st = c_start[lvl];
        const float rx = refp[((size_t)bq * NL_ + lvl) * 2 + 0];
        const float ry = refp[((size_t)bq * NL_ + lvl) * 2 + 1];
        const float ox = off[(size_t)bq * 256 + h * 32 + lvl * 8 + p * 2 + 0];
        const float oy = off[(size_t)bq * 256 + h * 32 + lvl * 8 + p * 2 + 1];
        const float x = rx * (float)Wi + ox - 0.5f;
        const float y = ry * (float)Hi + oy - 0.5f;

        const float x0f = floorf(x), y0f = floorf(y);
        const int   x0 = (int)x0f,   y0 = (int)y0f;
        const float wx1 = x - x0f, wx0 = 1.f - wx1;
        const float wy1 = y - y0f, wy0 = 1.f - wy1;

        const int   cx[4] = {x0, x0 + 1, x0,     x0 + 1};
        const int   cy[4] = {y0, y0,     y0 + 1, y0 + 1};
        const float cw[4] = {wx0 * wy0, wx1 * wy0, wx0 * wy1, wx1 * wy1};
#pragma unroll
        for (int c = 0; c < 4; ++c) {
            const bool inb = (cx[c] >= 0) & (cx[c] < Wi) & (cy[c] >= 0) & (cy[c] < Hi);
            sIdx[ql][t128][c] = inb ? (st + cy[c] * Wi + cx[c]) : -1;
            sW[ql][t128][c]   = wgt * cw[c];
        }
    }
    __syncthreads();

    const int h  = (tid >> 4) & 7;
    const int dp = tid & 15;
    const __hip_bfloat16* vbase = val + (size_t)b * S_ * 256 + h * 32 + dp * 2;

    float ax = 0.f, ay = 0.f;
#pragma unroll
    for (int lp = 0; lp < 16; ++lp) {
        const int e = h * 16 + lp;
#pragma unroll
        for (int c = 0; c < 4; ++c) {
            const int idx = sIdx[ql][e][c];
            if (idx >= 0) {
                const float w = sW[ql][e][c];
                const ushort2 u = *reinterpret_cast<const ushort2*>(vbase + (size_t)idx * 256);
                ax += w * __uint_as_float((unsigned)u.x << 16);
                ay += w * __uint_as_float((unsigned)u.y << 16);
            }
        }
    }
    __hip_bfloat16* ap = acc + (size_t)bq * 256 + h * 32 + dp * 2;
    ap[0] = __float2bfloat16(ax);
    ap[1] = __float2bfloat16(ay);
}

// ---------------------------------------------------------------------------
extern "C" void kernel_launch(void* const* d_in, const int* in_sizes, int n_in,
                              void* d_out, int out_size, void* d_ws, size_t ws_size,
                              hipStream_t stream) {
    const float* query  = (const float*)d_in[0];   // [B,L,256]
    const float* refp   = (const float*)d_in[1];   // [B,L,4,2]
    const float* value  = (const float*)d_in[2];   // [B,S,256]
    const float* W_val  = (const float*)d_in[3];   // [256,256]
    const float* b_val  = (const float*)d_in[4];
    const float* W_off  = (const float*)d_in[5];   // [256,256]
    const float* b_off  = (const float*)d_in[6];
    const float* W_attn = (const float*)d_in[7];   // [256,128]
    const float* b_attn = (const float*)d_in[8];
    const float* W_out  = (const float*)d_in[9];   // [256,256]
    const float* b_out  = (const float*)d_in[10];
    float* out = (float*)d_out;                    // [B,L,256]

    // workspace carve-up (16B aligned chunks)
    char* ws = (char*)d_ws;
    const size_t mb = (size_t)M_ * 256;
    __hip_bfloat16* q_bf    = (__hip_bfloat16*)ws;                 ws += mb * 2;
    __hip_bfloat16* v_bf    = (__hip_bfloat16*)ws;                 ws += mb * 2;
    __hip_bfloat16* val_bf  = (__hip_bfloat16*)ws;                 ws += mb * 2;
    __hip_bfloat16* acc_bf  = (__hip_bfloat16*)ws;                 ws += mb * 2;
    float*          off_f   = (float*)ws;                         ws += mb * 4;
    float*          attn_f  = (float*)ws;                         ws += (size_t)M_ * 128 * 4;
    __hip_bfloat16* wt_val  = (__hip_bfloat16*)ws;                 ws += 256 * 256 * 2;
    __hip_bfloat16* wt_off  = (__hip_bfloat16*)ws;                 ws += 256 * 256 * 2;
    __hip_bfloat16* wt_attn = (__hip_bfloat16*)ws;                 ws += 128 * 256 * 2;
    __hip_bfloat16* wt_out  = (__hip_bfloat16*)ws;                 ws += 256 * 256 * 2;

    const int M = M_;
    dim3 blk(256);

    // converts
    f32_to_bf16<<<1024, blk, 0, stream>>>(query, q_bf, (int)(mb / 4));
    f32_to_bf16<<<1024, blk, 0, stream>>>(value, v_bf, (int)(mb / 4));
    transpose_w_bf16<<<(256 * 256 + 255) / 256, blk, 0, stream>>>(W_val,  wt_val,  256, 256);
    transpose_w_bf16<<<(256 * 256 + 255) / 256, blk, 0, stream>>>(W_off,  wt_off,  256, 256);
    transpose_w_bf16<<<(128 * 256 + 255) / 256, blk, 0, stream>>>(W_attn, wt_attn, 256, 128);
    transpose_w_bf16<<<(256 * 256 + 255) / 256, blk, 0, stream>>>(W_out,  wt_out,  256, 256);

    const dim3 g256((M + 127) / 128, 2);
    const dim3 g128((M + 127) / 128, 1);

    // 1. value projection -> bf16 val
    gemm_mfma<__hip_bfloat16><<<g256, blk, 0, stream>>>(v_bf, wt_val, b_val, val_bf, M, 256);
    // 2. offset projection -> fp32
    gemm_mfma<float><<<g256, blk, 0, stream>>>(q_bf, wt_off, b_off, off_f, M, 256);
    // 3. attention logits -> fp32
    gemm_mfma<float><<<g128, blk, 0, stream>>>(q_bf, wt_attn, b_attn, attn_f, M, 128);
    // 4. softmax + bilinear sampling -> bf16 acc
    deform_sample_bf16<<<dim3(M / 2), blk, 0, stream>>>(val_bf, refp, off_f, attn_f, acc_bf);
    // 5. output projection -> fp32 out
    gemm_mfma<float><<<g256, blk, 0, stream>>>(acc_bf, wt_out, b_out, out, M, 256);
}

// Round 3
// 239.959 us; speedup vs baseline: 2.3351x; 1.3255x over previous
//
#include <hip/hip_runtime.h>
#include <hip/hip_bf16.h>
#include <math.h>

// Problem constants
#define B_    2
#define D_    256
#define NH_   8
#define NL_   4
#define NP_   4
#define HD_   32
#define S_    13294
#define L_    13294
#define M_    (B_ * L_)   // 26588 rows for all row-major GEMMs

__device__ __constant__ int c_H[NL_]     = {100, 50, 25, 13};
__device__ __constant__ int c_W[NL_]     = {100, 50, 25, 13};
__device__ __constant__ int c_start[NL_] = {0, 10000, 12500, 13125};

typedef __attribute__((ext_vector_type(8))) short  short8;   // 8 bf16
typedef __attribute__((ext_vector_type(4))) float  float4v;  // MFMA acc

// fp32 -> bf16 bits, round-to-nearest-even
__device__ __forceinline__ unsigned short f2bf(float f) {
    unsigned u = __float_as_uint(f);
    unsigned r = 0x7fffu + ((u >> 16) & 1u);
    return (unsigned short)((u + r) >> 16);
}
__device__ __forceinline__ float bflo(int u) {          // low bf16 of packed int
    return __uint_as_float((unsigned)u << 16);
}
__device__ __forceinline__ float bfhi(int u) {          // high bf16
    return __uint_as_float((unsigned)u & 0xffff0000u);
}

// ---------------------------------------------------------------------------
// Weight prep: transpose all W's to [N][K] bf16, build fused off|attn bias.
//   wt_val[256*256], wt_oa[384*256] (rows 0-255 off, 256-383 attn),
//   wt_out[256*256], bias_oa[384]
// ---------------------------------------------------------------------------
__global__ __launch_bounds__(256) void prep_weights(
    const float* __restrict__ W_val, const float* __restrict__ W_off,
    const float* __restrict__ W_attn, const float* __restrict__ b_off,
    const float* __restrict__ b_attn, const float* __restrict__ W_out,
    unsigned short* __restrict__ wt_val, unsigned short* __restrict__ wt_oa,
    unsigned short* __restrict__ wt_out, float* __restrict__ bias_oa)
{
    int i = blockIdx.x * 256 + threadIdx.x;
    if (i < 65536) {
        int n = i >> 8, k = i & 255;
        wt_val[i] = f2bf(W_val[k * 256 + n]);
    } else if (i < 65536 + 98304) {
        int j = i - 65536;
        int n = j >> 8, k = j & 255;   // n in [0,384)
        float v = (n < 256) ? W_off[k * 256 + n] : W_attn[k * 128 + (n - 256)];
        wt_oa[j] = f2bf(v);
    } else if (i < 65536 + 98304 + 65536) {
        int j = i - 163840;
        int n = j >> 8, k = j & 255;
        wt_out[j] = f2bf(W_out[k * 256 + n]);
    } else if (i < 229376 + 384) {
        int j = i - 229376;
        bias_oa[j] = (j < 256) ? b_off[j] : b_attn[j - 256];
    }
}

// ---------------------------------------------------------------------------
// bf16 MFMA GEMM: C[M,N] = A[M,256] * WT[N,256]^T + bias[N]
// 128x128 tile, 256 threads (4 waves 2x2), 16x16x32 bf16 MFMA.
// A_F32: A is fp32, converted to bf16 during LDS staging (fused convert).
// OUT_BF16: C stored as bf16 bits; else fp32.
// LDS rows padded to 40 bf16: conflict-free b128 reads.
// ---------------------------------------------------------------------------
template <bool A_F32, bool OUT_BF16>
__global__ __launch_bounds__(256) void gemm_mfma(
    const void* __restrict__ Av,
    const unsigned short* __restrict__ WT,
    const float* __restrict__ bias,
    void* __restrict__ Cv,
    int M, int N)
{
    __shared__ unsigned short As[128][40];
    __shared__ unsigned short Bs[128][40];

    const int tid  = threadIdx.x;
    const int lane = tid & 63;
    const int wave = tid >> 6;
    const int rowBase = blockIdx.x * 128;
    const int colBase = blockIdx.y * 128;
    const int wm = (wave >> 1) * 64;
    const int wn = (wave & 1) * 64;

    float4v acc[4][4] = {};

    const int fr = lane & 15;
    const int fk = (lane >> 4) * 8;

    for (int k0 = 0; k0 < 256; k0 += 32) {
        __syncthreads();
#pragma unroll
        for (int i = 0; i < 2; ++i) {
            const int c  = tid + i * 256;
            const int r  = c >> 2;          // 0..127
            const int ko = (c & 3) * 8;     // 0,8,16,24
            const int gr = rowBase + r;
            short8 va = {};
            if (gr < M) {
                if constexpr (A_F32) {
                    const float* Ap = (const float*)Av + (size_t)gr * 256 + k0 + ko;
                    float4 f0 = *reinterpret_cast<const float4*>(Ap);
                    float4 f1 = *reinterpret_cast<const float4*>(Ap + 4);
                    va[0] = (short)f2bf(f0.x); va[1] = (short)f2bf(f0.y);
                    va[2] = (short)f2bf(f0.z); va[3] = (short)f2bf(f0.w);
                    va[4] = (short)f2bf(f1.x); va[5] = (short)f2bf(f1.y);
                    va[6] = (short)f2bf(f1.z); va[7] = (short)f2bf(f1.w);
                } else {
                    va = *reinterpret_cast<const short8*>(
                        (const unsigned short*)Av + (size_t)gr * 256 + k0 + ko);
                }
            }
            *reinterpret_cast<short8*>(&As[r][ko]) = va;
            const int gc = colBase + r;     // N multiple of 128
            short8 vb = *reinterpret_cast<const short8*>(WT + (size_t)gc * 256 + k0 + ko);
            *reinterpret_cast<short8*>(&Bs[r][ko]) = vb;
        }
        __syncthreads();

        short8 af[4], bf[4];
#pragma unroll
        for (int t = 0; t < 4; ++t) {
            af[t] = *reinterpret_cast<const short8*>(&As[wm + t * 16 + fr][fk]);
            bf[t] = *reinterpret_cast<const short8*>(&Bs[wn + t * 16 + fr][fk]);
        }
#pragma unroll
        for (int mt = 0; mt < 4; ++mt)
#pragma unroll
            for (int nt = 0; nt < 4; ++nt)
                acc[mt][nt] = __builtin_amdgcn_mfma_f32_16x16x32_bf16(
                    af[mt], bf[nt], acc[mt][nt], 0, 0, 0);
    }

    const int dn  = lane & 15;
    const int dm0 = (lane >> 4) * 4;
#pragma unroll
    for (int mt = 0; mt < 4; ++mt) {
#pragma unroll
        for (int nt = 0; nt < 4; ++nt) {
            const int col = colBase + wn + nt * 16 + dn;
            const float bv = bias[col];
#pragma unroll
            for (int r = 0; r < 4; ++r) {
                const int row = rowBase + wm + mt * 16 + dm0 + r;
                if (row < M) {
                    const float v = acc[mt][nt][r] + bv;
                    if constexpr (OUT_BF16)
                        ((unsigned short*)Cv)[(size_t)row * N + col] = f2bf(v);
                    else
                        ((float*)Cv)[(size_t)row * N + col] = v;
                }
            }
        }
    }
}

// ---------------------------------------------------------------------------
// Deformable sampling v2: 8 queries/block, 256 threads.
//   Phase 1: 4 entities/thread: softmax weight + 4 corners -> packed (idx, w)
//            int2 in LDS (layout [q][c][lp][h] padded h->9: conflict-free).
//            OOB corner -> weight 0 (branch-free phase 2).
//   Phase 2: thread = (q, h, d4): 64 x dwordx4 gathers (16B/lane), fp32
//            accumulate 8 channels, one 16B bf16 store.
// ---------------------------------------------------------------------------
__global__ __launch_bounds__(256) void deform_sample_v2(
    const unsigned short* __restrict__ val,  // [B,S,256] bf16 bits
    const float* __restrict__ refp,          // [B,L,4,2]
    const float* __restrict__ oa,            // [M,384]: 0-255 off, 256-383 logits
    unsigned short* __restrict__ acc)        // [B,L,256] bf16 bits
{
    const int tid = threadIdx.x;
    const int q0  = blockIdx.x * 8;

    __shared__ float sLog[8][128];
    __shared__ int2  sPack[8][4][16][9];

    // stage logits (cols 256..383 of oa)
    {
        const int q  = tid >> 5;
        const int f  = tid & 31;
        const int bq = min(q0 + q, M_ - 1);
        float4 v = *reinterpret_cast<const float4*>(oa + (size_t)bq * 384 + 256 + f * 4);
        *reinterpret_cast<float4*>(&sLog[q][f * 4]) = v;
    }
    __syncthreads();

    // phase 1
#pragma unroll
    for (int k = 0; k < 4; ++k) {
        const int e   = tid + k * 256;
        const int q   = e >> 7;
        const int t   = e & 127;
        const int h   = t >> 4;
        const int lp  = t & 15;
        const int lvl = lp >> 2;
        const int p   = lp & 3;
        const int bq  = min(q0 + q, M_ - 1);

        float m = -1e30f;
#pragma unroll
        for (int i = 0; i < 16; ++i) m = fmaxf(m, sLog[q][h * 16 + i]);
        float s = 0.f;
#pragma unroll
        for (int i = 0; i < 16; ++i) s += __expf(sLog[q][h * 16 + i] - m);
        const float wgt = __expf(sLog[q][t] - m) / s;

        const int Wi = c_W[lvl], Hi = c_H[lvl], st = c_start[lvl];
        const float rx = refp[((size_t)bq * NL_ + lvl) * 2 + 0];
        const float ry = refp[((size_t)bq * NL_ + lvl) * 2 + 1];
        const float ox = oa[(size_t)bq * 384 + h * 32 + lvl * 8 + p * 2 + 0];
        const float oy = oa[(size_t)bq * 384 + h * 32 + lvl * 8 + p * 2 + 1];
        const float x = rx * (float)Wi + ox - 0.5f;
        const float y = ry * (float)Hi + oy - 0.5f;

        const float x0f = floorf(x), y0f = floorf(y);
        const int   x0 = (int)x0f,   y0 = (int)y0f;
        const float wx1 = x - x0f, wx0 = 1.f - wx1;
        const float wy1 = y - y0f, wy0 = 1.f - wy1;

        const int   cx[4] = {x0, x0 + 1, x0,     x0 + 1};
        const int   cy[4] = {y0, y0,     y0 + 1, y0 + 1};
        const float cw[4] = {wx0 * wy0, wx1 * wy0, wx0 * wy1, wx1 * wy1};
#pragma unroll
        for (int c = 0; c < 4; ++c) {
            const bool inb = (cx[c] >= 0) & (cx[c] < Wi) & (cy[c] >= 0) & (cy[c] < Hi);
            const int xi = min(max(cx[c], 0), Wi - 1);
            const int yi = min(max(cy[c], 0), Hi - 1);
            int2 pk;
            pk.x = st + yi * Wi + xi;
            pk.y = __float_as_int(inb ? wgt * cw[c] : 0.f);
            sPack[q][c][lp][h] = pk;
        }
    }
    __syncthreads();

    // phase 2
    const int q  = tid >> 5;
    const int h  = (tid >> 2) & 7;
    const int d4 = tid & 3;
    const int bq = q0 + q;
    const int b  = min(bq, M_ - 1) / L_;
    const unsigned short* vb = val + (size_t)b * S_ * 256 + h * 32 + d4 * 8;

    float a0 = 0, a1 = 0, a2 = 0, a3 = 0, a4 = 0, a5 = 0, a6 = 0, a7 = 0;
#pragma unroll 4
    for (int lp = 0; lp < 16; ++lp) {
#pragma unroll
        for (int c = 0; c < 4; ++c) {
            const int2 pk = sPack[q][c][lp][h];
            const float w = __int_as_float(pk.y);
            const int4 u = *reinterpret_cast<const int4*>(vb + (size_t)pk.x * 256);
            a0 += w * bflo(u.x); a1 += w * bfhi(u.x);
            a2 += w * bflo(u.y); a3 += w * bfhi(u.y);
            a4 += w * bflo(u.z); a5 += w * bfhi(u.z);
            a6 += w * bflo(u.w); a7 += w * bfhi(u.w);
        }
    }
    if (bq < M_) {
        int4 o;
        o.x = (int)f2bf(a0) | ((int)f2bf(a1) << 16);
        o.y = (int)f2bf(a2) | ((int)f2bf(a3) << 16);
        o.z = (int)f2bf(a4) | ((int)f2bf(a5) << 16);
        o.w = (int)f2bf(a6) | ((int)f2bf(a7) << 16);
        *reinterpret_cast<int4*>(acc + (size_t)bq * 256 + h * 32 + d4 * 8) = o;
    }
}

// ---------------------------------------------------------------------------
extern "C" void kernel_launch(void* const* d_in, const int* in_sizes, int n_in,
                              void* d_out, int out_size, void* d_ws, size_t ws_size,
                              hipStream_t stream) {
    const float* query  = (const float*)d_in[0];
    const float* refp   = (const float*)d_in[1];
    const float* value  = (const float*)d_in[2];
    const float* W_val  = (const float*)d_in[3];
    const float* b_val  = (const float*)d_in[4];
    const float* W_off  = (const float*)d_in[5];
    const float* b_off  = (const float*)d_in[6];
    const float* W_attn = (const float*)d_in[7];
    const float* b_attn = (const float*)d_in[8];
    const float* W_out  = (const float*)d_in[9];
    const float* b_out  = (const float*)d_in[10];
    float* out = (float*)d_out;

    char* ws = (char*)d_ws;
    const size_t mb = (size_t)M_ * 256;
    unsigned short* val_bf  = (unsigned short*)ws;  ws += mb * 2;
    unsigned short* acc_bf  = (unsigned short*)ws;  ws += mb * 2;
    float*          oa_f    = (float*)ws;           ws += (size_t)M_ * 384 * 4;
    unsigned short* wt_val  = (unsigned short*)ws;  ws += 65536 * 2;
    unsigned short* wt_oa   = (unsigned short*)ws;  ws += 98304 * 2;
    unsigned short* wt_out  = (unsigned short*)ws;  ws += 65536 * 2;
    float*          bias_oa = (float*)ws;           ws += 384 * 4;

    const int M = M_;
    dim3 blk(256);

    prep_weights<<<dim3(898), blk, 0, stream>>>(
        W_val, W_off, W_attn, b_off, b_attn, W_out, wt_val, wt_oa, wt_out, bias_oa);

    const dim3 gV((M + 127) / 128, 2);   // N=256
    const dim3 gOA((M + 127) / 128, 3);  // N=384

    // 1. value projection (fp32 A, bf16 out)
    gemm_mfma<true, true><<<gV, blk, 0, stream>>>(value, wt_val, b_val, val_bf, M, 256);
    // 2. fused offset+logits projection (fp32 A, fp32 out)
    gemm_mfma<true, false><<<gOA, blk, 0, stream>>>(query, wt_oa, bias_oa, oa_f, M, 384);
    // 3. softmax + bilinear sampling (bf16 gathers)
    deform_sample_v2<<<dim3((M + 7) / 8), blk, 0, stream>>>(val_bf, refp, oa_f, acc_bf);
    // 4. output projection (bf16 A, fp32 out)
    gemm_mfma<false, false><<<gV, blk, 0, stream>>>(acc_bf, wt_out, b_out, out, M, 256);
}

// Round 4
// 212.195 us; speedup vs baseline: 2.6406x; 1.1308x over previous
//
#include <hip/hip_runtime.h>
#include <hip/hip_bf16.h>
#include <math.h>

// Problem constants
#define B_    2
#define D_    256
#define NH_   8
#define NL_   4
#define NP_   4
#define HD_   32
#define S_    13294
#define L_    13294
#define M_    (B_ * L_)   // 26588

__device__ __constant__ int c_H[NL_]     = {100, 50, 25, 13};
__device__ __constant__ int c_W[NL_]     = {100, 50, 25, 13};
__device__ __constant__ int c_start[NL_] = {0, 10000, 12500, 13125};

typedef __attribute__((ext_vector_type(8))) short  short8;   // 8 bf16
typedef __attribute__((ext_vector_type(4))) float  float4v;  // MFMA acc

__device__ __forceinline__ unsigned short f2bf(float f) {
    unsigned u = __float_as_uint(f);
    unsigned r = 0x7fffu + ((u >> 16) & 1u);
    return (unsigned short)((u + r) >> 16);
}
__device__ __forceinline__ float bflo(int u) { return __uint_as_float((unsigned)u << 16); }
__device__ __forceinline__ float bfhi(int u) { return __uint_as_float((unsigned)u & 0xffff0000u); }
__device__ __forceinline__ unsigned short f2h(float f) {
    _Float16 h = (_Float16)f;
    return __builtin_bit_cast(unsigned short, h);
}
__device__ __forceinline__ float h2f(unsigned short u) {
    _Float16 h = __builtin_bit_cast(_Float16, u);
    return (float)h;
}

// ---------------------------------------------------------------------------
// Weight prep: transpose W's to [N][K] bf16, fused off|attn weights + bias.
// ---------------------------------------------------------------------------
__global__ __launch_bounds__(256) void prep_weights(
    const float* __restrict__ W_val, const float* __restrict__ W_off,
    const float* __restrict__ W_attn, const float* __restrict__ b_off,
    const float* __restrict__ b_attn, const float* __restrict__ W_out,
    unsigned short* __restrict__ wt_val, unsigned short* __restrict__ wt_oa,
    unsigned short* __restrict__ wt_out, float* __restrict__ bias_oa)
{
    int i = blockIdx.x * 256 + threadIdx.x;
    if (i < 65536) {
        int n = i >> 8, k = i & 255;
        wt_val[i] = f2bf(W_val[k * 256 + n]);
    } else if (i < 65536 + 98304) {
        int j = i - 65536;
        int n = j >> 8, k = j & 255;   // n in [0,384)
        float v = (n < 256) ? W_off[k * 256 + n] : W_attn[k * 128 + (n - 256)];
        wt_oa[j] = f2bf(v);
    } else if (i < 65536 + 98304 + 65536) {
        int j = i - 163840;
        int n = j >> 8, k = j & 255;
        wt_out[j] = f2bf(W_out[k * 256 + n]);
    } else if (i < 229376 + 384) {
        int j = i - 229376;
        bias_oa[j] = (j < 256) ? b_off[j] : b_attn[j - 256];
    }
}

// ---------------------------------------------------------------------------
// Fused GEMM dispatch: 128x64 tiles, 256 threads (4 waves 2x2: 64x32 each).
// blockIdx.y < 4  : val_bf[.,y*64..]  = value @ wt_val^T + b_val   (bf16 out)
// blockIdx.y >= 4 : oa_f[.,(y-4)*64..] = query @ wt_oa^T + bias_oa (fp32 out)
// A is fp32, converted to bf16 during LDS staging.
// ---------------------------------------------------------------------------
__global__ __launch_bounds__(256) void gemm_fused(
    const float* __restrict__ value, const float* __restrict__ query,
    const unsigned short* __restrict__ wt_val, const unsigned short* __restrict__ wt_oa,
    const float* __restrict__ b_val, const float* __restrict__ bias_oa,
    unsigned short* __restrict__ val_bf, float* __restrict__ oa_f)
{
    __shared__ unsigned short As[128][40];
    __shared__ unsigned short Bs[64][40];

    const int tid  = threadIdx.x;
    const int lane = tid & 63;
    const int wave = tid >> 6;
    const int rowBase = blockIdx.x * 128;
    const int y = blockIdx.y;

    const float* A;
    const unsigned short* WT;
    const float* bias;
    int N, colBase;
    bool outBF16;
    if (y < 4) { A = value; WT = wt_val; bias = b_val;   N = 256; colBase = y * 64;      outBF16 = true;  }
    else       { A = query; WT = wt_oa;  bias = bias_oa; N = 384; colBase = (y - 4) * 64; outBF16 = false; }

    const int wm = (wave >> 1) * 64;
    const int wn = (wave & 1) * 32;

    float4v acc[4][2] = {};
    const int fr = lane & 15;
    const int fk = (lane >> 4) * 8;

    for (int k0 = 0; k0 < 256; k0 += 32) {
        __syncthreads();
        // A: 512 chunks (128 rows x 4), 2 per thread, fp32->bf16
#pragma unroll
        for (int i = 0; i < 2; ++i) {
            const int c  = tid + i * 256;
            const int r  = c >> 2;
            const int ko = (c & 3) * 8;
            const int gr = rowBase + r;
            short8 va = {};
            if (gr < M_) {
                const float* Ap = A + (size_t)gr * 256 + k0 + ko;
                float4 f0 = *reinterpret_cast<const float4*>(Ap);
                float4 f1 = *reinterpret_cast<const float4*>(Ap + 4);
                va[0] = (short)f2bf(f0.x); va[1] = (short)f2bf(f0.y);
                va[2] = (short)f2bf(f0.z); va[3] = (short)f2bf(f0.w);
                va[4] = (short)f2bf(f1.x); va[5] = (short)f2bf(f1.y);
                va[6] = (short)f2bf(f1.z); va[7] = (short)f2bf(f1.w);
            }
            *reinterpret_cast<short8*>(&As[r][ko]) = va;
        }
        // B: 256 chunks (64 rows x 4), 1 per thread
        {
            const int r  = tid >> 2;
            const int ko = (tid & 3) * 8;
            short8 vb = *reinterpret_cast<const short8*>(
                WT + (size_t)(colBase + r) * 256 + k0 + ko);
            *reinterpret_cast<short8*>(&Bs[r][ko]) = vb;
        }
        __syncthreads();

        short8 af[4], bf[2];
#pragma unroll
        for (int t = 0; t < 4; ++t)
            af[t] = *reinterpret_cast<const short8*>(&As[wm + t * 16 + fr][fk]);
#pragma unroll
        for (int t = 0; t < 2; ++t)
            bf[t] = *reinterpret_cast<const short8*>(&Bs[wn + t * 16 + fr][fk]);
#pragma unroll
        for (int mt = 0; mt < 4; ++mt)
#pragma unroll
            for (int nt = 0; nt < 2; ++nt)
                acc[mt][nt] = __builtin_amdgcn_mfma_f32_16x16x32_bf16(
                    af[mt], bf[nt], acc[mt][nt], 0, 0, 0);
    }

    const int dn  = lane & 15;
    const int dm0 = (lane >> 4) * 4;
#pragma unroll
    for (int mt = 0; mt < 4; ++mt) {
#pragma unroll
        for (int nt = 0; nt < 2; ++nt) {
            const int col = colBase + wn + nt * 16 + dn;
            const float bv = bias[col];
#pragma unroll
            for (int r = 0; r < 4; ++r) {
                const int row = rowBase + wm + mt * 16 + dm0 + r;
                if (row < M_) {
                    const float v = acc[mt][nt][r] + bv;
                    if (outBF16)
                        val_bf[(size_t)row * 256 + col] = f2bf(v);
                    else
                        oa_f[(size_t)row * 384 + col] = v;
                }
            }
        }
    }
}

// ---------------------------------------------------------------------------
// Output GEMM: out[M,256] = acc_bf[M,256] @ wt_out^T + b_out. 128x64 tiles.
// ---------------------------------------------------------------------------
__global__ __launch_bounds__(256) void gemm_out(
    const unsigned short* __restrict__ Abf,
    const unsigned short* __restrict__ WT,
    const float* __restrict__ bias,
    float* __restrict__ C)
{
    __shared__ unsigned short As[128][40];
    __shared__ unsigned short Bs[64][40];

    const int tid  = threadIdx.x;
    const int lane = tid & 63;
    const int wave = tid >> 6;
    const int rowBase = blockIdx.x * 128;
    const int colBase = blockIdx.y * 64;

    const int wm = (wave >> 1) * 64;
    const int wn = (wave & 1) * 32;

    float4v acc[4][2] = {};
    const int fr = lane & 15;
    const int fk = (lane >> 4) * 8;

    for (int k0 = 0; k0 < 256; k0 += 32) {
        __syncthreads();
#pragma unroll
        for (int i = 0; i < 2; ++i) {
            const int c  = tid + i * 256;
            const int r  = c >> 2;
            const int ko = (c & 3) * 8;
            const int gr = rowBase + r;
            short8 va = {};
            if (gr < M_)
                va = *reinterpret_cast<const short8*>(Abf + (size_t)gr * 256 + k0 + ko);
            *reinterpret_cast<short8*>(&As[r][ko]) = va;
        }
        {
            const int r  = tid >> 2;
            const int ko = (tid & 3) * 8;
            short8 vb = *reinterpret_cast<const short8*>(
                WT + (size_t)(colBase + r) * 256 + k0 + ko);
            *reinterpret_cast<short8*>(&Bs[r][ko]) = vb;
        }
        __syncthreads();

        short8 af[4], bf[2];
#pragma unroll
        for (int t = 0; t < 4; ++t)
            af[t] = *reinterpret_cast<const short8*>(&As[wm + t * 16 + fr][fk]);
#pragma unroll
        for (int t = 0; t < 2; ++t)
            bf[t] = *reinterpret_cast<const short8*>(&Bs[wn + t * 16 + fr][fk]);
#pragma unroll
        for (int mt = 0; mt < 4; ++mt)
#pragma unroll
            for (int nt = 0; nt < 2; ++nt)
                acc[mt][nt] = __builtin_amdgcn_mfma_f32_16x16x32_bf16(
                    af[mt], bf[nt], acc[mt][nt], 0, 0, 0);
    }

    const int dn  = lane & 15;
    const int dm0 = (lane >> 4) * 4;
#pragma unroll
    for (int mt = 0; mt < 4; ++mt) {
#pragma unroll
        for (int nt = 0; nt < 2; ++nt) {
            const int col = colBase + wn + nt * 16 + dn;
            const float bv = bias[col];
#pragma unroll
            for (int r = 0; r < 4; ++r) {
                const int row = rowBase + wm + mt * 16 + dm0 + r;
                if (row < M_)
                    C[(size_t)row * 256 + col] = acc[mt][nt][r] + bv;
            }
        }
    }
}

// ---------------------------------------------------------------------------
// Deformable sampling v3: 8 queries/block, 256 threads, 20.5 KB LDS.
//   Stage logits -> per-(q,h) softmax max/inv-sum pre-pass (64 threads) ->
//   1024 entities pack (idx:16 | w_fp16:16) into 4-B LDS entries ->
//   phase 2: (q,h,d4) threads, 64 dwordx4 gathers, fp32 accum, bf16 store.
// ---------------------------------------------------------------------------
__global__ __launch_bounds__(256) void deform_sample_v3(
    const unsigned short* __restrict__ val,  // [B,S,256] bf16 bits
    const float* __restrict__ refp,          // [B,L,4,2]
    const float* __restrict__ oa,            // [M,384]
    unsigned short* __restrict__ acc)        // [B,L,256] bf16 bits
{
    const int tid = threadIdx.x;
    const int q0  = blockIdx.x * 8;

    __shared__ float sLog[8][128];         // 4 KB
    __shared__ float sMS[8][8][2];         // 512 B: max, inv-sum
    __shared__ int   sPack[8][4][16][8];   // 16 KB

    // stage logits
    {
        const int q  = tid >> 5;
        const int f  = tid & 31;
        const int bq = min(q0 + q, M_ - 1);
        float4 v = *reinterpret_cast<const float4*>(oa + (size_t)bq * 384 + 256 + f * 4);
        *reinterpret_cast<float4*>(&sLog[q][f * 4]) = v;
    }
    __syncthreads();

    // per-(q,h) softmax max / inv-sum
    if (tid < 64) {
        const int q = tid >> 3, h = tid & 7;
        float m = -1e30f;
#pragma unroll
        for (int i = 0; i < 16; ++i) m = fmaxf(m, sLog[q][h * 16 + i]);
        float s = 0.f;
#pragma unroll
        for (int i = 0; i < 16; ++i) s += __expf(sLog[q][h * 16 + i] - m);
        sMS[q][h][0] = m;
        sMS[q][h][1] = 1.f / s;
    }
    __syncthreads();

    // phase 1: 1024 entities, 4 per thread
#pragma unroll
    for (int k = 0; k < 4; ++k) {
        const int e   = tid + k * 256;
        const int q   = e >> 7;
        const int t   = e & 127;
        const int h   = t >> 4;
        const int lp  = t & 15;
        const int lvl = lp >> 2;
        const int p   = lp & 3;
        const int bq  = min(q0 + q, M_ - 1);

        const float wgt = __expf(sLog[q][t] - sMS[q][h][0]) * sMS[q][h][1];

        const int Wi = c_W[lvl], Hi = c_H[lvl], st = c_start[lvl];
        const float rx = refp[((size_t)bq * NL_ + lvl) * 2 + 0];
        const float ry = refp[((size_t)bq * NL_ + lvl) * 2 + 1];
        const float ox = oa[(size_t)bq * 384 + h * 32 + lvl * 8 + p * 2 + 0];
        const float oy = oa[(size_t)bq * 384 + h * 32 + lvl * 8 + p * 2 + 1];
        const float x = rx * (float)Wi + ox - 0.5f;
        const float y = ry * (float)Hi + oy - 0.5f;

        const float x0f = floorf(x), y0f = floorf(y);
        const int   x0 = (int)x0f,   y0 = (int)y0f;
        const float wx1 = x - x0f, wx0 = 1.f - wx1;
        const float wy1 = y - y0f, wy0 = 1.f - wy1;

        const int   cx[4] = {x0, x0 + 1, x0,     x0 + 1};
        const int   cy[4] = {y0, y0,     y0 + 1, y0 + 1};
        const float cw[4] = {wx0 * wy0, wx1 * wy0, wx0 * wy1, wx1 * wy1};
#pragma unroll
        for (int c = 0; c < 4; ++c) {
            const bool inb = (cx[c] >= 0) & (cx[c] < Wi) & (cy[c] >= 0) & (cy[c] < Hi);
            const int xi = min(max(cx[c], 0), Wi - 1);
            const int yi = min(max(cy[c], 0), Hi - 1);
            const int idx = st + yi * Wi + xi;                      // < 13294, fits 16 bits
            const unsigned short wh = f2h(inb ? wgt * cw[c] : 0.f);
            sPack[q][c][lp][h] = idx | ((int)wh << 16);
        }
    }
    __syncthreads();

    // phase 2
    const int q  = tid >> 5;
    const int h  = (tid >> 2) & 7;
    const int d4 = tid & 3;
    const int bq = q0 + q;
    const int b  = min(bq, M_ - 1) / L_;
    const unsigned short* vb = val + (size_t)b * S_ * 256 + h * 32 + d4 * 8;

    float a0 = 0, a1 = 0, a2 = 0, a3 = 0, a4 = 0, a5 = 0, a6 = 0, a7 = 0;
#pragma unroll 8
    for (int i = 0; i < 64; ++i) {
        const int lp = i >> 2;
        const int c  = i & 3;
        const int pk = sPack[q][c][lp][h];
        const float w = h2f((unsigned short)((unsigned)pk >> 16));
        const unsigned idx = (unsigned)pk & 0xffffu;
        const int4 u = *reinterpret_cast<const int4*>(vb + (size_t)idx * 256);
        a0 += w * bflo(u.x); a1 += w * bfhi(u.x);
        a2 += w * bflo(u.y); a3 += w * bfhi(u.y);
        a4 += w * bflo(u.z); a5 += w * bfhi(u.z);
        a6 += w * bflo(u.w); a7 += w * bfhi(u.w);
    }
    if (bq < M_) {
        int4 o;
        o.x = (int)f2bf(a0) | ((int)f2bf(a1) << 16);
        o.y = (int)f2bf(a2) | ((int)f2bf(a3) << 16);
        o.z = (int)f2bf(a4) | ((int)f2bf(a5) << 16);
        o.w = (int)f2bf(a6) | ((int)f2bf(a7) << 16);
        *reinterpret_cast<int4*>(acc + (size_t)bq * 256 + h * 32 + d4 * 8) = o;
    }
}

// ---------------------------------------------------------------------------
extern "C" void kernel_launch(void* const* d_in, const int* in_sizes, int n_in,
                              void* d_out, int out_size, void* d_ws, size_t ws_size,
                              hipStream_t stream) {
    const float* query  = (const float*)d_in[0];
    const float* refp   = (const float*)d_in[1];
    const float* value  = (const float*)d_in[2];
    const float* W_val  = (const float*)d_in[3];
    const float* b_val  = (const float*)d_in[4];
    const float* W_off  = (const float*)d_in[5];
    const float* b_off  = (const float*)d_in[6];
    const float* W_attn = (const float*)d_in[7];
    const float* b_attn = (const float*)d_in[8];
    const float* W_out  = (const float*)d_in[9];
    const float* b_out  = (const float*)d_in[10];
    float* out = (float*)d_out;

    char* ws = (char*)d_ws;
    const size_t mb = (size_t)M_ * 256;
    unsigned short* val_bf  = (unsigned short*)ws;  ws += mb * 2;
    unsigned short* acc_bf  = (unsigned short*)ws;  ws += mb * 2;
    float*          oa_f    = (float*)ws;           ws += (size_t)M_ * 384 * 4;
    unsigned short* wt_val  = (unsigned short*)ws;  ws += 65536 * 2;
    unsigned short* wt_oa   = (unsigned short*)ws;  ws += 98304 * 2;
    unsigned short* wt_out  = (unsigned short*)ws;  ws += 65536 * 2;
    float*          bias_oa = (float*)ws;           ws += 384 * 4;

    dim3 blk(256);

    prep_weights<<<dim3(898), blk, 0, stream>>>(
        W_val, W_off, W_attn, b_off, b_attn, W_out, wt_val, wt_oa, wt_out, bias_oa);

    // value proj + off/attn proj, one dispatch: grid (208, 10) = 2080 blocks
    gemm_fused<<<dim3((M_ + 127) / 128, 10), blk, 0, stream>>>(
        value, query, wt_val, wt_oa, b_val, bias_oa, val_bf, oa_f);

    // softmax + sampling
    deform_sample_v3<<<dim3((M_ + 7) / 8), blk, 0, stream>>>(val_bf, refp, oa_f, acc_bf);

    // output projection
    gemm_out<<<dim3((M_ + 127) / 128, 4), blk, 0, stream>>>(acc_bf, wt_out, b_out, out);
}

// Round 5
// 207.640 us; speedup vs baseline: 2.6985x; 1.0219x over previous
//
#include <hip/hip_runtime.h>
#include <hip/hip_bf16.h>
#include <math.h>

// Problem constants
#define B_    2
#define NH_   8
#define NL_   4
#define NP_   4
#define HD_   32
#define S_    13294
#define L_    13294
#define M_    26588

__device__ __constant__ int c_H[NL_]     = {100, 50, 25, 13};
__device__ __constant__ int c_W[NL_]     = {100, 50, 25, 13};
__device__ __constant__ int c_start[NL_] = {0, 10000, 12500, 13125};

typedef __attribute__((ext_vector_type(8))) short  short8;   // 8 bf16
typedef __attribute__((ext_vector_type(4))) float  float4v;  // MFMA acc

__device__ __forceinline__ unsigned short f2bf(float f) {
    unsigned u = __float_as_uint(f);
    unsigned r = 0x7fffu + ((u >> 16) & 1u);
    return (unsigned short)((u + r) >> 16);
}
__device__ __forceinline__ unsigned short f2h(float f) {
    _Float16 h = (_Float16)f;
    return __builtin_bit_cast(unsigned short, h);
}
__device__ __forceinline__ float h2f(unsigned short u) {
    _Float16 h = __builtin_bit_cast(_Float16, u);
    return (float)h;
}

// ---------------------------------------------------------------------------
// Weight prep: transpose W's to [N][K] bf16, fused off|attn weights + bias.
// ---------------------------------------------------------------------------
__global__ __launch_bounds__(256) void prep_weights(
    const float* __restrict__ W_val, const float* __restrict__ W_off,
    const float* __restrict__ W_attn, const float* __restrict__ b_off,
    const float* __restrict__ b_attn, const float* __restrict__ W_out,
    unsigned short* __restrict__ wt_val, unsigned short* __restrict__ wt_oa,
    unsigned short* __restrict__ wt_out, float* __restrict__ bias_oa)
{
    int i = blockIdx.x * 256 + threadIdx.x;
    if (i < 65536) {
        int n = i >> 8, k = i & 255;
        wt_val[i] = f2bf(W_val[k * 256 + n]);
    } else if (i < 65536 + 98304) {
        int j = i - 65536;
        int n = j >> 8, k = j & 255;   // n in [0,384)
        float v = (n < 256) ? W_off[k * 256 + n] : W_attn[k * 128 + (n - 256)];
        wt_oa[j] = f2bf(v);
    } else if (i < 65536 + 98304 + 65536) {
        int j = i - 163840;
        int n = j >> 8, k = j & 255;
        wt_out[j] = f2bf(W_out[k * 256 + n]);
    } else if (i < 229376 + 384) {
        int j = i - 229376;
        bias_oa[j] = (j < 256) ? b_off[j] : b_attn[j - 256];
    }
}

// ---------------------------------------------------------------------------
// Software-pipelined MFMA GEMM body.
//   Tile: 64 rows x N cols per block (A read exactly once).
//   4 waves, wave w = 64 rows x N/4 cols (4 x NT 16x16 tiles).
//   K-loop: 8 iters of BK=32; iter k+1's global loads issued before iter k's
//   MFMAs (register prefetch) so load latency overlaps compute.
//   OUT: 0 = fp16 store stride 256, 1 = fp32 store stride 384,
//        2 = fp32 store stride 256.
// ---------------------------------------------------------------------------
template<int N, int OUT, bool AF32>
__device__ __forceinline__ void gemm_body(
    const void* __restrict__ Av,
    const unsigned short* __restrict__ WT,
    const float* __restrict__ bias,
    void* __restrict__ Cv,
    unsigned short (* __restrict__ As)[40],
    unsigned short (* __restrict__ Bs)[40])
{
    constexpr int NT  = N / 64;    // n-tiles per wave (4 or 6)
    constexpr int NCH = N / 64;    // B chunks per thread (4 or 6)

    const int tid  = threadIdx.x;
    const int lane = tid & 63;
    const int wave = tid >> 6;
    const int rowBase = blockIdx.x * 64;
    const int wcol = wave * (N / 4);

    const int ar   = tid >> 2;          // 0..63: A row
    const int ako  = (tid & 3) * 8;     // k offset within BK
    const int grow = rowBase + ar;

    float4v acc[4][NT] = {};
    float4 pa0, pa1;
    short8 pah;
    short8 pb[NCH];

    auto loadAB = [&](int k0) {
        if constexpr (AF32) {
            const float* A = (const float*)Av;
            if (grow < M_) {
                pa0 = *reinterpret_cast<const float4*>(A + (size_t)grow * 256 + k0 + ako);
                pa1 = *reinterpret_cast<const float4*>(A + (size_t)grow * 256 + k0 + ako + 4);
            } else {
                pa0 = make_float4(0.f, 0.f, 0.f, 0.f); pa1 = pa0;
            }
        } else {
            const unsigned short* A = (const unsigned short*)Av;
            if (grow < M_)
                pah = *reinterpret_cast<const short8*>(A + (size_t)grow * 256 + k0 + ako);
            else
                pah = short8{};
        }
#pragma unroll
        for (int i = 0; i < NCH; ++i) {
            const int c = tid + i * 256;
            pb[i] = *reinterpret_cast<const short8*>(
                WT + (size_t)(c >> 2) * 256 + k0 + (c & 3) * 8);
        }
    };

    auto storeLDS = [&]() {
        short8 s;
        if constexpr (AF32) {
            s[0] = (short)f2bf(pa0.x); s[1] = (short)f2bf(pa0.y);
            s[2] = (short)f2bf(pa0.z); s[3] = (short)f2bf(pa0.w);
            s[4] = (short)f2bf(pa1.x); s[5] = (short)f2bf(pa1.y);
            s[6] = (short)f2bf(pa1.z); s[7] = (short)f2bf(pa1.w);
        } else {
            s = pah;
        }
        *reinterpret_cast<short8*>(&As[ar][ako]) = s;
#pragma unroll
        for (int i = 0; i < NCH; ++i) {
            const int c = tid + i * 256;
            *reinterpret_cast<short8*>(&Bs[c >> 2][(c & 3) * 8]) = pb[i];
        }
    };

    const int fr = lane & 15;
    const int fk = (lane >> 4) * 8;

    loadAB(0);
#pragma unroll
    for (int it = 0; it < 8; ++it) {
        __syncthreads();
        storeLDS();
        __syncthreads();
        if (it < 7) loadAB((it + 1) * 32);   // in-flight during MFMAs below

        short8 af[4], bf[NT];
#pragma unroll
        for (int t = 0; t < 4; ++t)
            af[t] = *reinterpret_cast<const short8*>(&As[t * 16 + fr][fk]);
#pragma unroll
        for (int t = 0; t < NT; ++t)
            bf[t] = *reinterpret_cast<const short8*>(&Bs[wcol + t * 16 + fr][fk]);
#pragma unroll
        for (int mt = 0; mt < 4; ++mt)
#pragma unroll
            for (int nt = 0; nt < NT; ++nt)
                acc[mt][nt] = __builtin_amdgcn_mfma_f32_16x16x32_bf16(
                    af[mt], bf[nt], acc[mt][nt], 0, 0, 0);
    }

    const int dn  = lane & 15;
    const int dm0 = (lane >> 4) * 4;
#pragma unroll
    for (int mt = 0; mt < 4; ++mt) {
#pragma unroll
        for (int nt = 0; nt < NT; ++nt) {
            const int col = wcol + nt * 16 + dn;
            const float bv = bias[col];
#pragma unroll
            for (int r = 0; r < 4; ++r) {
                const int row = rowBase + mt * 16 + dm0 + r;
                if (row < M_) {
                    const float v = acc[mt][nt][r] + bv;
                    if constexpr (OUT == 0)
                        ((unsigned short*)Cv)[(size_t)row * 256 + col] = f2h(v);
                    else if constexpr (OUT == 1)
                        ((float*)Cv)[(size_t)row * 384 + col] = v;
                    else
                        ((float*)Cv)[(size_t)row * 256 + col] = v;
                }
            }
        }
    }
}

// value proj (y=0, fp16 out) + query off/attn proj (y=1, fp32 out), merged.
__global__ __launch_bounds__(256) void gemm_vq(
    const float* __restrict__ value, const float* __restrict__ query,
    const unsigned short* __restrict__ wt_val, const unsigned short* __restrict__ wt_oa,
    const float* __restrict__ b_val, const float* __restrict__ bias_oa,
    unsigned short* __restrict__ val_f16, float* __restrict__ oa_f)
{
    __shared__ unsigned short As[64][40];
    __shared__ unsigned short Bs[384][40];
    if (blockIdx.y == 0)
        gemm_body<256, 0, true>(value, wt_val, b_val, val_f16, As, Bs);
    else
        gemm_body<384, 1, true>(query, wt_oa, bias_oa, oa_f, As, Bs);
}

// output projection: out = acc_bf @ wt_out^T + b_out
__global__ __launch_bounds__(256) void gemm_out2(
    const unsigned short* __restrict__ Abf,
    const unsigned short* __restrict__ WT,
    const float* __restrict__ bias, float* __restrict__ C)
{
    __shared__ unsigned short As[64][40];
    __shared__ unsigned short Bs[256][40];
    gemm_body<256, 2, false>(Abf, WT, bias, C, As, Bs);
}

// ---------------------------------------------------------------------------
// Deformable sampling v4: 8 queries/block, 256 threads, fp16 val gathers.
// ---------------------------------------------------------------------------
__global__ __launch_bounds__(256) void deform_sample_v4(
    const unsigned short* __restrict__ val,  // [B,S,256] fp16 bits
    const float* __restrict__ refp,          // [B,L,4,2]
    const float* __restrict__ oa,            // [M,384]
    unsigned short* __restrict__ acc)        // [B,L,256] bf16 bits
{
    const int tid = threadIdx.x;
    const int q0  = blockIdx.x * 8;

    __shared__ float sLog[8][128];
    __shared__ float sMS[8][8][2];
    __shared__ int   sPack[8][4][16][8];

    {
        const int q  = tid >> 5;
        const int f  = tid & 31;
        const int bq = min(q0 + q, M_ - 1);
        float4 v = *reinterpret_cast<const float4*>(oa + (size_t)bq * 384 + 256 + f * 4);
        *reinterpret_cast<float4*>(&sLog[q][f * 4]) = v;
    }
    __syncthreads();

    if (tid < 64) {
        const int q = tid >> 3, h = tid & 7;
        float m = -1e30f;
#pragma unroll
        for (int i = 0; i < 16; ++i) m = fmaxf(m, sLog[q][h * 16 + i]);
        float s = 0.f;
#pragma unroll
        for (int i = 0; i < 16; ++i) s += __expf(sLog[q][h * 16 + i] - m);
        sMS[q][h][0] = m;
        sMS[q][h][1] = 1.f / s;
    }
    __syncthreads();

#pragma unroll
    for (int k = 0; k < 4; ++k) {
        const int e   = tid + k * 256;
        const int q   = e >> 7;
        const int t   = e & 127;
        const int h   = t >> 4;
        const int lp  = t & 15;
        const int lvl = lp >> 2;
        const int p   = lp & 3;
        const int bq  = min(q0 + q, M_ - 1);

        const float wgt = __expf(sLog[q][t] - sMS[q][h][0]) * sMS[q][h][1];

        const int Wi = c_W[lvl], Hi = c_H[lvl], st = c_start[lvl];
        const float rx = refp[((size_t)bq * NL_ + lvl) * 2 + 0];
        const float ry = refp[((size_t)bq * NL_ + lvl) * 2 + 1];
        const float ox = oa[(size_t)bq * 384 + h * 32 + lvl * 8 + p * 2 + 0];
        const float oy = oa[(size_t)bq * 384 + h * 32 + lvl * 8 + p * 2 + 1];
        const float x = rx * (float)Wi + ox - 0.5f;
        const float y = ry * (float)Hi + oy - 0.5f;

        const float x0f = floorf(x), y0f = floorf(y);
        const int   x0 = (int)x0f,   y0 = (int)y0f;
        const float wx1 = x - x0f, wx0 = 1.f - wx1;
        const float wy1 = y - y0f, wy0 = 1.f - wy1;

        const int   cx[4] = {x0, x0 + 1, x0,     x0 + 1};
        const int   cy[4] = {y0, y0,     y0 + 1, y0 + 1};
        const float cw[4] = {wx0 * wy0, wx1 * wy0, wx0 * wy1, wx1 * wy1};
#pragma unroll
        for (int c = 0; c < 4; ++c) {
            const bool inb = (cx[c] >= 0) & (cx[c] < Wi) & (cy[c] >= 0) & (cy[c] < Hi);
            const int xi = min(max(cx[c], 0), Wi - 1);
            const int yi = min(max(cy[c], 0), Hi - 1);
            const int idx = st + yi * Wi + xi;          // < 13294: fits 16 bits
            const unsigned short wh = f2h(inb ? wgt * cw[c] : 0.f);
            sPack[q][c][lp][h] = idx | ((int)wh << 16);
        }
    }
    __syncthreads();

    const int q  = tid >> 5;
    const int h  = (tid >> 2) & 7;
    const int d4 = tid & 3;
    const int bq = q0 + q;
    const int b  = min(bq, M_ - 1) / L_;
    const unsigned short* vb = val + (size_t)b * S_ * 256 + h * 32 + d4 * 8;

    float a0 = 0, a1 = 0, a2 = 0, a3 = 0, a4 = 0, a5 = 0, a6 = 0, a7 = 0;
#pragma unroll 8
    for (int i = 0; i < 64; ++i) {
        const int lp = i >> 2;
        const int c  = i & 3;
        const int pk = sPack[q][c][lp][h];
        const float w = h2f((unsigned short)((unsigned)pk >> 16));
        const unsigned idx = (unsigned)pk & 0xffffu;
        const int4 u = *reinterpret_cast<const int4*>(vb + (size_t)idx * 256);
        a0 += w * h2f((unsigned short)(u.x & 0xffff));
        a1 += w * h2f((unsigned short)((unsigned)u.x >> 16));
        a2 += w * h2f((unsigned short)(u.y & 0xffff));
        a3 += w * h2f((unsigned short)((unsigned)u.y >> 16));
        a4 += w * h2f((unsigned short)(u.z & 0xffff));
        a5 += w * h2f((unsigned short)((unsigned)u.z >> 16));
        a6 += w * h2f((unsigned short)(u.w & 0xffff));
        a7 += w * h2f((unsigned short)((unsigned)u.w >> 16));
    }
    if (bq < M_) {
        int4 o;
        o.x = (int)f2bf(a0) | ((int)f2bf(a1) << 16);
        o.y = (int)f2bf(a2) | ((int)f2bf(a3) << 16);
        o.z = (int)f2bf(a4) | ((int)f2bf(a5) << 16);
        o.w = (int)f2bf(a6) | ((int)f2bf(a7) << 16);
        *reinterpret_cast<int4*>(acc + (size_t)bq * 256 + h * 32 + d4 * 8) = o;
    }
}

// ---------------------------------------------------------------------------
extern "C" void kernel_launch(void* const* d_in, const int* in_sizes, int n_in,
                              void* d_out, int out_size, void* d_ws, size_t ws_size,
                              hipStream_t stream) {
    const float* query  = (const float*)d_in[0];
    const float* refp   = (const float*)d_in[1];
    const float* value  = (const float*)d_in[2];
    const float* W_val  = (const float*)d_in[3];
    const float* b_val  = (const float*)d_in[4];
    const float* W_off  = (const float*)d_in[5];
    const float* b_off  = (const float*)d_in[6];
    const float* W_attn = (const float*)d_in[7];
    const float* b_attn = (const float*)d_in[8];
    const float* W_out  = (const float*)d_in[9];
    const float* b_out  = (const float*)d_in[10];
    float* out = (float*)d_out;

    char* ws = (char*)d_ws;
    const size_t mb = (size_t)M_ * 256;
    unsigned short* val_f16 = (unsigned short*)ws;  ws += mb * 2;
    unsigned short* acc_bf  = (unsigned short*)ws;  ws += mb * 2;
    float*          oa_f    = (float*)ws;           ws += (size_t)M_ * 384 * 4;
    unsigned short* wt_val  = (unsigned short*)ws;  ws += 65536 * 2;
    unsigned short* wt_oa   = (unsigned short*)ws;  ws += 98304 * 2;
    unsigned short* wt_out  = (unsigned short*)ws;  ws += 65536 * 2;
    float*          bias_oa = (float*)ws;           ws += 384 * 4;

    dim3 blk(256);

    prep_weights<<<dim3(898), blk, 0, stream>>>(
        W_val, W_off, W_attn, b_off, b_attn, W_out, wt_val, wt_oa, wt_out, bias_oa);

    // value proj + off/attn proj: 64-row tiles, A read once, pipelined K-loop
    gemm_vq<<<dim3((M_ + 63) / 64, 2), blk, 0, stream>>>(
        value, query, wt_val, wt_oa, b_val, bias_oa, val_f16, oa_f);

    // softmax + sampling (fp16 gathers)
    deform_sample_v4<<<dim3((M_ + 7) / 8), blk, 0, stream>>>(val_f16, refp, oa_f, acc_bf);

    // output projection
    gemm_out2<<<dim3((M_ + 63) / 64), blk, 0, stream>>>(acc_bf, wt_out, b_out, out);
}

// Round 7
// 207.259 us; speedup vs baseline: 2.7035x; 1.0018x over previous
//
#include <hip/hip_runtime.h>
#include <hip/hip_bf16.h>
#include <math.h>

// Problem constants
#define B_    2
#define NH_   8
#define NL_   4
#define NP_   4
#define HD_   32
#define S_    13294
#define L_    13294
#define M_    26588

__device__ __constant__ int c_H[NL_]     = {100, 50, 25, 13};
__device__ __constant__ int c_W[NL_]     = {100, 50, 25, 13};
__device__ __constant__ int c_start[NL_] = {0, 10000, 12500, 13125};

typedef __attribute__((ext_vector_type(8))) _Float16 f16x8;
typedef __attribute__((ext_vector_type(2))) _Float16 f16x2;
typedef __attribute__((ext_vector_type(4))) float    float4v;

__device__ __forceinline__ unsigned short f2h(float f) {
    _Float16 h = (_Float16)f;
    return __builtin_bit_cast(unsigned short, h);
}
__device__ __forceinline__ float h2f(unsigned short u) {
    _Float16 h = __builtin_bit_cast(_Float16, u);
    return (float)h;
}
__device__ __forceinline__ f16x2 pkrtz(float a, float b) {
    return __builtin_bit_cast(f16x2, __builtin_amdgcn_cvt_pkrtz(a, b));
}

// ---------------------------------------------------------------------------
// Weight prep: transpose W's to [N][K] fp16, fused off|attn weights + bias.
// ---------------------------------------------------------------------------
__global__ __launch_bounds__(256) void prep_weights(
    const float* __restrict__ W_val, const float* __restrict__ W_off,
    const float* __restrict__ W_attn, const float* __restrict__ b_off,
    const float* __restrict__ b_attn, const float* __restrict__ W_out,
    unsigned short* __restrict__ wt_val, unsigned short* __restrict__ wt_oa,
    unsigned short* __restrict__ wt_out, float* __restrict__ bias_oa)
{
    int i = blockIdx.x * 256 + threadIdx.x;
    if (i < 65536) {
        int n = i >> 8, k = i & 255;
        wt_val[i] = f2h(W_val[k * 256 + n]);
    } else if (i < 65536 + 98304) {
        int j = i - 65536;
        int n = j >> 8, k = j & 255;   // n in [0,384)
        float v = (n < 256) ? W_off[k * 256 + n] : W_attn[k * 128 + (n - 256)];
        wt_oa[j] = f2h(v);
    } else if (i < 65536 + 98304 + 65536) {
        int j = i - 163840;
        int n = j >> 8, k = j & 255;
        wt_out[j] = f2h(W_out[k * 256 + n]);
    } else if (i < 229376 + 384) {
        int j = i - 229376;
        bias_oa[j] = (j < 256) ? b_off[j] : b_attn[j - 256];
    }
}

// ---------------------------------------------------------------------------
// MFMA GEMM body, f16, B-direct-from-global.
//   Tile: 64 rows x N cols per block; wave w owns cols [w*N/4, (w+1)*N/4).
//   A: LDS, double-buffered (As[2][64][40]), ONE barrier per K-iter.
//   B: no LDS — each lane's fragment is a contiguous 16B global load,
//      register-prefetched one full iteration ahead (vmcnt slack ~1 iter).
//   OUT: 0 = fp16 stride 256, 1 = fp16 stride 384, 2 = fp32 stride 256.
// ---------------------------------------------------------------------------
template<int N, int OUT, bool AF32>
__device__ __forceinline__ void gemm_body(
    const void* __restrict__ Av,
    const unsigned short* __restrict__ WT,
    const float* __restrict__ bias,
    void* __restrict__ Cv,
    unsigned short (* __restrict__ As)[64][40])
{
    constexpr int NT = N / 64;      // B fragments per wave (4 or 6)

    const int tid  = threadIdx.x;
    const int lane = tid & 63;
    const int wave = tid >> 6;
    const int rowBase = blockIdx.x * 64;
    const int wcol = wave * (N / 4);

    const int ar   = tid >> 2;          // A row within tile
    const int ako  = (tid & 3) * 8;     // k offset within BK=32
    const int grow = rowBase + ar;
    const int fr   = lane & 15;
    const int fk   = (lane >> 4) * 8;

    float4v acc[4][NT] = {};

    const unsigned short* bbase[NT];
#pragma unroll
    for (int t = 0; t < NT; ++t)
        bbase[t] = WT + (size_t)(wcol + t * 16 + fr) * 256 + fk;

    f16x8 curB[NT], nxtB[NT];
    float4 ra0, ra1;
    f16x8  rah;

    auto loadA = [&](int k0) {
        if constexpr (AF32) {
            const float* A = (const float*)Av;
            if (grow < M_) {
                ra0 = *reinterpret_cast<const float4*>(A + (size_t)grow * 256 + k0 + ako);
                ra1 = *reinterpret_cast<const float4*>(A + (size_t)grow * 256 + k0 + ako + 4);
            } else { ra0 = make_float4(0.f,0.f,0.f,0.f); ra1 = ra0; }
        } else {
            const unsigned short* A = (const unsigned short*)Av;
            if (grow < M_)
                rah = *reinterpret_cast<const f16x8*>(A + (size_t)grow * 256 + k0 + ako);
            else
                rah = f16x8{};
        }
    };
    auto storeA = [&](int buf) {
        f16x8 s;
        if constexpr (AF32) {
            f16x2 p0 = pkrtz(ra0.x, ra0.y);
            f16x2 p1 = pkrtz(ra0.z, ra0.w);
            f16x2 p2 = pkrtz(ra1.x, ra1.y);
            f16x2 p3 = pkrtz(ra1.z, ra1.w);
            s[0]=p0[0]; s[1]=p0[1]; s[2]=p1[0]; s[3]=p1[1];
            s[4]=p2[0]; s[5]=p2[1]; s[6]=p3[0]; s[7]=p3[1];
        } else {
            s = rah;
        }
        *reinterpret_cast<f16x8*>(&As[buf][ar][ako]) = s;
    };
    auto loadB = [&](f16x8* dst, int k0) {
#pragma unroll
        for (int t = 0; t < NT; ++t)
            dst[t] = *reinterpret_cast<const f16x8*>(bbase[t] + k0);
    };

    // prologue
    loadA(0);
    loadB(curB, 0);
    storeA(0);
    loadA(32);

#pragma unroll
    for (int it = 0; it < 8; ++it) {
        __syncthreads();                       // As[it&1] ready for all waves
        f16x8 af[4];
#pragma unroll
        for (int t = 0; t < 4; ++t)
            af[t] = *reinterpret_cast<const f16x8*>(&As[it & 1][t * 16 + fr][fk]);
        if (it < 7) {
            storeA((it + 1) & 1);              // regs loaded at it-1 -> full-iter slack
            if (it < 6) loadA((it + 2) * 32);
            loadB(nxtB, (it + 1) * 32);        // in flight across the MFMAs below
        }
#pragma unroll
        for (int mt = 0; mt < 4; ++mt)
#pragma unroll
            for (int nt = 0; nt < NT; ++nt)
                acc[mt][nt] = __builtin_amdgcn_mfma_f32_16x16x32_f16(
                    af[mt], curB[nt], acc[mt][nt], 0, 0, 0);
        if (it < 7) {
#pragma unroll
            for (int t = 0; t < NT; ++t) curB[t] = nxtB[t];
        }
    }

    const int dn  = lane & 15;
    const int dm0 = (lane >> 4) * 4;
#pragma unroll
    for (int mt = 0; mt < 4; ++mt) {
#pragma unroll
        for (int nt = 0; nt < NT; ++nt) {
            const int col = wcol + nt * 16 + dn;
            const float bv = bias[col];
#pragma unroll
            for (int r = 0; r < 4; ++r) {
                const int row = rowBase + mt * 16 + dm0 + r;
                if (row < M_) {
                    const float v = acc[mt][nt][r] + bv;
                    if constexpr (OUT == 0)
                        ((unsigned short*)Cv)[(size_t)row * 256 + col] = f2h(v);
                    else if constexpr (OUT == 1)
                        ((unsigned short*)Cv)[(size_t)row * 384 + col] = f2h(v);
                    else
                        ((float*)Cv)[(size_t)row * 256 + col] = v;
                }
            }
        }
    }
}

// value proj (y=0, fp16 out) + query off/attn proj (y=1, fp16 out), merged.
__global__ __launch_bounds__(256) void gemm_vq(
    const float* __restrict__ value, const float* __restrict__ query,
    const unsigned short* __restrict__ wt_val, const unsigned short* __restrict__ wt_oa,
    const float* __restrict__ b_val, const float* __restrict__ bias_oa,
    unsigned short* __restrict__ val_f16, unsigned short* __restrict__ oa_f16)
{
    __shared__ unsigned short As[2][64][40];
    if (blockIdx.y == 0)
        gemm_body<256, 0, true>(value, wt_val, b_val, val_f16, As);
    else
        gemm_body<384, 1, true>(query, wt_oa, bias_oa, oa_f16, As);
}

// output projection: out = acc_f16 @ wt_out^T + b_out (fp32 out)
__global__ __launch_bounds__(256) void gemm_out3(
    const unsigned short* __restrict__ Af16,
    const unsigned short* __restrict__ WT,
    const float* __restrict__ bias, float* __restrict__ C)
{
    __shared__ unsigned short As[2][64][40];
    gemm_body<256, 2, false>(Af16, WT, bias, C, As);
}

// ---------------------------------------------------------------------------
// Deformable sampling v5: 8 queries/block, 256 threads, 18.5 KB LDS.
//   Phase 2 inner loop: 1 ds_read_b32 + 1 global dwordx4 + 4 v_pk_fma_f16;
//   fp16-pair accumulators stored directly (no epilogue converts).
// ---------------------------------------------------------------------------
__global__ __launch_bounds__(256) void deform_sample_v5(
    const unsigned short* __restrict__ val,  // [B,S,256] fp16
    const float* __restrict__ refp,          // [B,L,4,2]
    const unsigned short* __restrict__ oa,   // [M,384] fp16
    unsigned short* __restrict__ acc)        // [M,256] fp16
{
    const int tid = threadIdx.x;
    const int q0  = blockIdx.x * 8;

    __shared__ unsigned short sLog[8][128];   // 2 KB
    __shared__ float sMS[8][8][2];            // 0.5 KB
    __shared__ int   sPack[8][4][16][8];      // 16 KB

    {
        const int q  = tid >> 5;
        const int f  = tid & 31;
        const int bq = min(q0 + q, M_ - 1);
        *reinterpret_cast<int2*>(&sLog[q][f * 4]) =
            *reinterpret_cast<const int2*>(oa + (size_t)bq * 384 + 256 + f * 4);
    }
    __syncthreads();

    if (tid < 64) {
        const int q = tid >> 3, h = tid & 7;
        float m = -1e30f;
#pragma unroll
        for (int i = 0; i < 16; ++i) m = fmaxf(m, h2f(sLog[q][h * 16 + i]));
        float s = 0.f;
#pragma unroll
        for (int i = 0; i < 16; ++i) s += __expf(h2f(sLog[q][h * 16 + i]) - m);
        sMS[q][h][0] = m;
        sMS[q][h][1] = 1.f / s;
    }
    __syncthreads();

#pragma unroll
    for (int k = 0; k < 4; ++k) {
        const int e   = tid + k * 256;
        const int q   = e >> 7;
        const int t   = e & 127;
        const int h   = t >> 4;
        const int lp  = t & 15;
        const int lvl = lp >> 2;
        const int p   = lp & 3;
        const int bq  = min(q0 + q, M_ - 1);

        const float wgt = __expf(h2f(sLog[q][t]) - sMS[q][h][0]) * sMS[q][h][1];

        const int Wi = c_W[lvl], Hi = c_H[lvl], st = c_start[lvl];
        const float rx = refp[((size_t)bq * NL_ + lvl) * 2 + 0];
        const float ry = refp[((size_t)bq * NL_ + lvl) * 2 + 1];
        const float ox = h2f(oa[(size_t)bq * 384 + h * 32 + lvl * 8 + p * 2 + 0]);
        const float oy = h2f(oa[(size_t)bq * 384 + h * 32 + lvl * 8 + p * 2 + 1]);
        const float x = rx * (float)Wi + ox - 0.5f;
        const float y = ry * (float)Hi + oy - 0.5f;

        const float x0f = floorf(x), y0f = floorf(y);
        const int   x0 = (int)x0f,   y0 = (int)y0f;
        const float wx1 = x - x0f, wx0 = 1.f - wx1;
        const float wy1 = y - y0f, wy0 = 1.f - wy1;

        const int   cx[4] = {x0, x0 + 1, x0,     x0 + 1};
        const int   cy[4] = {y0, y0,     y0 + 1, y0 + 1};
        const float cw[4] = {wx0 * wy0, wx1 * wy0, wx0 * wy1, wx1 * wy1};
#pragma unroll
        for (int c = 0; c < 4; ++c) {
            const bool inb = (cx[c] >= 0) & (cx[c] < Wi) & (cy[c] >= 0) & (cy[c] < Hi);
            const int xi = min(max(cx[c], 0), Wi - 1);
            const int yi = min(max(cy[c], 0), Hi - 1);
            const int idx = st + yi * Wi + xi;          // < 13294: fits 16 bits
            const unsigned short wh = f2h(inb ? wgt * cw[c] : 0.f);
            sPack[q][c][lp][h] = idx | ((int)wh << 16);
        }
    }
    __syncthreads();

    const int q  = tid >> 5;
    const int h  = (tid >> 2) & 7;
    const int d4 = tid & 3;
    const int bq = q0 + q;
    const int b  = min(bq, M_ - 1) / L_;
    const unsigned short* vb = val + (size_t)b * S_ * 256 + h * 32 + d4 * 8;

    f16x2 A0{}, A1{}, A2{}, A3{};
#pragma unroll 8
    for (int i = 0; i < 64; ++i) {
        const int lp = i >> 2;
        const int c  = i & 3;
        const int pk = sPack[q][c][lp][h];
        const unsigned wb = (unsigned)pk >> 16;
        const f16x2 w2 = __builtin_bit_cast(f16x2, (wb << 16) | wb);
        const int4 u = *reinterpret_cast<const int4*>(
            vb + (size_t)((unsigned)pk & 0xffffu) * 256);
        A0 += w2 * __builtin_bit_cast(f16x2, u.x);
        A1 += w2 * __builtin_bit_cast(f16x2, u.y);
        A2 += w2 * __builtin_bit_cast(f16x2, u.z);
        A3 += w2 * __builtin_bit_cast(f16x2, u.w);
    }
    if (bq < M_) {
        int4 o;
        o.x = __builtin_bit_cast(int, A0);
        o.y = __builtin_bit_cast(int, A1);
        o.z = __builtin_bit_cast(int, A2);
        o.w = __builtin_bit_cast(int, A3);
        *reinterpret_cast<int4*>(acc + (size_t)bq * 256 + h * 32 + d4 * 8) = o;
    }
}

// ---------------------------------------------------------------------------
extern "C" void kernel_launch(void* const* d_in, const int* in_sizes, int n_in,
                              void* d_out, int out_size, void* d_ws, size_t ws_size,
                              hipStream_t stream) {
    const float* query  = (const float*)d_in[0];
    const float* refp   = (const float*)d_in[1];
    const float* value  = (const float*)d_in[2];
    const float* W_val  = (const float*)d_in[3];
    const float* b_val  = (const float*)d_in[4];
    const float* W_off  = (const float*)d_in[5];
    const float* b_off  = (const float*)d_in[6];
    const float* W_attn = (const float*)d_in[7];
    const float* b_attn = (const float*)d_in[8];
    const float* W_out  = (const float*)d_in[9];
    const float* b_out  = (const float*)d_in[10];
    float* out = (float*)d_out;

    char* ws = (char*)d_ws;
    const size_t mb = (size_t)M_ * 256;
    unsigned short* val_f16 = (unsigned short*)ws;  ws += mb * 2;
    unsigned short* acc_f16 = (unsigned short*)ws;  ws += mb * 2;
    unsigned short* oa_f16  = (unsigned short*)ws;  ws += (size_t)M_ * 384 * 2;
    unsigned short* wt_val  = (unsigned short*)ws;  ws += 65536 * 2;
    unsigned short* wt_oa   = (unsigned short*)ws;  ws += 98304 * 2;
    unsigned short* wt_out  = (unsigned short*)ws;  ws += 65536 * 2;
    float*          bias_oa = (float*)ws;           ws += 384 * 4;

    dim3 blk(256);

    prep_weights<<<dim3(898), blk, 0, stream>>>(
        W_val, W_off, W_attn, b_off, b_attn, W_out, wt_val, wt_oa, wt_out, bias_oa);

    // value proj + off/attn proj (one dispatch, 832 blocks)
    gemm_vq<<<dim3((M_ + 63) / 64, 2), blk, 0, stream>>>(
        value, query, wt_val, wt_oa, b_val, bias_oa, val_f16, oa_f16);

    // softmax + sampling (fp16 end-to-end)
    deform_sample_v5<<<dim3((M_ + 7) / 8), blk, 0, stream>>>(val_f16, refp, oa_f16, acc_f16);

    // output projection
    gemm_out3<<<dim3((M_ + 63) / 64), blk, 0, stream>>>(acc_f16, wt_out, b_out, out);
}